// Round 1
// baseline (65.248 us; speedup 1.0000x reference)
//
#include <hip/hip_runtime.h>

#define NREG   20
#define EDIM   768
#define DVOL   64
#define HVOL   512
#define WVOL   512
#define HW_    (HVOL * WVOL)
#define DHW_   (DVOL * HVOL * WVOL)
#define NPATCH 16384
#define BTOT   2
#define PROTO_N (NREG * EDIM)            // 15360
#define RF_N    (BTOT * PROTO_N)         // 30720 floats (output 0)
#define TOTAL_PATCHES (BTOT * NPATCH)    // 32768

// ---------------------------------------------------------------------------
// Output 0: region_features = prototypes broadcast to (B, 20, 768)
// ---------------------------------------------------------------------------
__global__ __launch_bounds__(256) void proto_copy_kernel(
    const float* __restrict__ proto, float* __restrict__ out)
{
    int i = blockIdx.x * 256 + threadIdx.x;
    if (i < RF_N) out[i] = proto[i % PROTO_N];
}

// ---------------------------------------------------------------------------
// Output 1: patch_to_region assignments. One wave per patch.
// Lane decomposition: xl = lane & 15 (x offset), yh = lane >> 4 (y sub-row).
// 16 iterations cover z in 0..3, y-block in 0..3  -> 1024 voxels / patch.
// Packed 8-bit per-lane histogram (5 regs x 4 regions), butterfly reduce.
// ---------------------------------------------------------------------------
__global__ __launch_bounds__(256) void assign_kernel(
    const int*   __restrict__ seg,
    const float* __restrict__ coords,
    float*       __restrict__ out)
{
    __shared__ float smem[4][NREG];

    const int lane  = threadIdx.x & 63;
    const int wave  = threadIdx.x >> 6;
    const int patch = blockIdx.x * 4 + wave;          // grid = 8192 -> exact
    const int b     = patch >> 14;                    // patch / NPATCH

    // --- crop box, exactly mirroring the reference float math -------------
    const float c0 = coords[patch * 3 + 0] * 64.0f;   // z
    const float c1 = coords[patch * 3 + 1] * 512.0f;  // y
    const float c2 = coords[patch * 3 + 2] * 512.0f;  // x

    const int sz = (int)fmaxf(0.0f,   floorf(c0 - 2.0f));
    const int ez = (int)fminf(64.0f,  floorf(c0 + 2.0f));
    const int sy = (int)fmaxf(0.0f,   floorf(c1 - 8.0f));
    const int ey = (int)fminf(512.0f, floorf(c1 + 8.0f));
    const int sx = (int)fmaxf(0.0f,   floorf(c2 - 8.0f));
    const int ex = (int)fminf(512.0f, floorf(c2 + 8.0f));

    // --- per-lane constants -------------------------------------------------
    const int xl  = lane & 15;
    const int yh  = lane >> 4;
    const int xi  = sx + xl;
    const int vx  = (xi < ex) ? 1 : 0;
    const int xiC = min(xi, WVOL - 1);
    const int base = b * DHW_;

    // packed 8-bit counters: cc[k] holds regions 4k..4k+3 (0-based region m)
    unsigned int cc[5] = {0u, 0u, 0u, 0u, 0u};

#pragma unroll
    for (int it = 0; it < 16; ++it) {
        const int z  = it >> 2;
        const int yb = it & 3;
        const int zi = sz + z;
        const int yi = sy + yb * 4 + yh;
        const int vz = (zi < ez) ? 1 : 0;
        const int vy = (yi < ey) ? 1 : 0;
        const int ziC = min(zi, DVOL - 1);
        const int yiC = min(yi, HVOL - 1);

        const int val = seg[base + ziC * HW_ + yiC * WVOL + xiC];
        // invalid -> 0 (region ids are 1..20; 0 is never counted)
        const int v = (vz & vy & vx) ? val : 0;

        const int t = v - 1;                       // -1 if not counted
        const unsigned int inc = 1u << ((t & 3) << 3);
        const int q = t >> 2;                      // arithmetic: -1 matches no k
#pragma unroll
        for (int k = 0; k < 5; ++k)
            cc[k] += (q == k) ? inc : 0u;
    }

    // --- unpack 8-bit -> 2x16-bit, butterfly-reduce across 64 lanes --------
    unsigned int lo[5], hi[5];
#pragma unroll
    for (int k = 0; k < 5; ++k) {
        lo[k] = cc[k] & 0x00FF00FFu;          // fields: m=4k (lo16), m=4k+2 (hi16)
        hi[k] = (cc[k] >> 8) & 0x00FF00FFu;   // fields: m=4k+1,       m=4k+3
    }
#pragma unroll
    for (int off = 1; off < 64; off <<= 1) {
#pragma unroll
        for (int k = 0; k < 5; ++k) {
            lo[k] += (unsigned int)__shfl_xor((int)lo[k], off);
            hi[k] += (unsigned int)__shfl_xor((int)hi[k], off);
        }
    }

    // total count over all 20 regions (every lane has the full result)
    unsigned int tot = 0u;
#pragma unroll
    for (int k = 0; k < 5; ++k)
        tot += (lo[k] & 0xFFFFu) + (lo[k] >> 16) + (hi[k] & 0xFFFFu) + (hi[k] >> 16);

    if (lane == 0) {
#pragma unroll
        for (int k = 0; k < 5; ++k) {
            smem[wave][4 * k + 0] = (float)(lo[k] & 0xFFFFu);
            smem[wave][4 * k + 1] = (float)(hi[k] & 0xFFFFu);
            smem[wave][4 * k + 2] = (float)(lo[k] >> 16);
            smem[wave][4 * k + 3] = (float)(hi[k] >> 16);
        }
    }
    __syncthreads();

    // --- normalization -----------------------------------------------------
    const float nz = (float)max(ez - sz, 0);
    const float ny = (float)max(ey - sy, 0);
    const float nx = (float)max(ex - sx, 0);
    const float numel = nz * ny * nx;
    const float denom = fmaxf(numel, 1.0f);
    const float s = (float)tot / denom + (float)NREG * 1e-6f;

    if (lane < NREG) {
        const float cnt = smem[wave][lane];
        const float a = cnt / denom + 1e-6f;
        out[RF_N + patch * NREG + lane] = a / s;
    }
}

// ---------------------------------------------------------------------------
extern "C" void kernel_launch(void* const* d_in, const int* in_sizes, int n_in,
                              void* d_out, int out_size, void* d_ws, size_t ws_size,
                              hipStream_t stream)
{
    const int*   seg    = (const int*)d_in[0];
    const float* coords = (const float*)d_in[1];
    const float* proto  = (const float*)d_in[2];
    float*       out    = (float*)d_out;

    hipLaunchKernelGGL(proto_copy_kernel, dim3(RF_N / 256), dim3(256), 0, stream,
                       proto, out);
    hipLaunchKernelGGL(assign_kernel, dim3(TOTAL_PATCHES / 4), dim3(256), 0, stream,
                       seg, coords, out);
}